// Round 10
// baseline (118.719 us; speedup 1.0000x reference)
//
#include <hip/hip_runtime.h>
#include <hip/hip_bf16.h>

typedef __attribute__((ext_vector_type(8))) short short8;
typedef __attribute__((ext_vector_type(4))) float f32x4;
typedef __attribute__((ext_vector_type(4))) unsigned u32x4;
typedef unsigned short u16;

#define AS1 __attribute__((address_space(1)))
#define AS3 __attribute__((address_space(3)))

#define LOG2E 1.44269504088896f
#define FOLD_M 46.166241308446828f   // 32 * log2(e)
#define EXP2(x) __builtin_amdgcn_exp2f(x)

// fp32 -> bf16 round-to-nearest-even
__device__ __forceinline__ u16 f2bf(float f) {
    unsigned u = __builtin_bit_cast(unsigned, f);
    u += 0x7FFFu + ((u >> 16) & 1u);
    return (u16)(u >> 16);
}

// two f32 -> packed bf16 pair (RNE, matches f2bf exactly)
__device__ __forceinline__ unsigned pkrne(float a, float b) {
    return (unsigned)f2bf(a) | ((unsigned)f2bf(b) << 16);
}

// pack two f32 -> two bf16 in one u32 (round-half-up + v_perm) — P-matrix only
__device__ __forceinline__ unsigned pk2(float a, float b) {
    unsigned ua = __builtin_bit_cast(unsigned, a) + 0x8000u;
    unsigned ub = __builtin_bit_cast(unsigned, b) + 0x8000u;
    return __builtin_amdgcn_perm(ub, ua, 0x07060302);  // [ub.b3 ub.b2 ua.b3 ua.b2]
}

// ---------------------------------------------------------------- prep:
// z<4: weight transposes; z==4: folded bias table
__global__ __launch_bounds__(256) void k_prep(const float* __restrict__ Wq, const float* __restrict__ Wk,
                                              const float* __restrict__ Wv, const float* __restrict__ Wo,
                                              const float* __restrict__ tbl,
                                              u16* __restrict__ wt, u16* __restrict__ wot,
                                              float* __restrict__ bias2) {
    int z = blockIdx.z;
    if (z == 4) {
        int idx = (blockIdx.y * 32 + blockIdx.x) * 256 + threadIdx.x;
        if (idx < 16 * 2048) {
            int r = idx & 2047, h = idx >> 11;
            int rel = r - 1023;
            int bucket = rel > 0 ? 16 : 0;
            int rp = rel < 0 ? -rel : rel;
            if (rp < 8) bucket += rp;
            else {
                int lb = 8 + (int)(log2f((float)rp * 0.125f) * 2.0f);
                bucket += (lb < 15 ? lb : 15);
            }
            bias2[idx] = tbl[bucket * 16 + h] * LOG2E - FOLD_M;
        }
        return;
    }
    const float* in = z == 0 ? Wq : z == 1 ? Wk : z == 2 ? Wv : Wo;
    u16* out = (z == 3) ? wot : wt + (size_t)z * 1024 * 1024;
    __shared__ float tile[32][33];
    int tx = threadIdx.x & 31, ty = threadIdx.x >> 5;
    int bx = blockIdx.x << 5, by = blockIdx.y << 5;
    #pragma unroll
    for (int j = 0; j < 32; j += 8)
        tile[ty + j][tx] = in[(size_t)(by + ty + j) * 1024 + bx + tx];
    __syncthreads();
    #pragma unroll
    for (int j = 0; j < 32; j += 8)
        out[(size_t)(bx + ty + j) * 1024 + by + tx] = f2bf(tile[tx][ty + j]);
}

// ---------------------------------------------------------------- QKV GEMM: 256x192 tile, 8 waves,
// BK=64, grid = 256 (1 block/CU). A staged DIRECTLY from fp32 hidden via reg-staging
// (T14: loads at iter top, convert+swizzled ds_write after compute); B via global_load_lds.
// LDS rows XOR-swizzled (byte ^= (row&7)<<4). 2D XCD chunking. Wave-tile 128x48.
// Epilogue scatters Q/K [B][H][S][64], Vt [B][H][64][S].
__global__ __launch_bounds__(512, 2) void k_qkv(const float* __restrict__ A32, const u16* __restrict__ Bt,
                                                u16* __restrict__ oq, u16* __restrict__ ok,
                                                u16* __restrict__ ov) {
    __shared__ __align__(16) u16 As[2][256 * 64];
    __shared__ __align__(16) u16 Bs[2][192 * 64];
    int t = threadIdx.x, lane = t & 63, wave = t >> 6;
    int g = lane >> 4, ln = lane & 15;
    int wr = wave >> 2, wc = wave & 3;            // 2M x 4N wave grid

    int bid = blockIdx.x;
    int xcd = bid & 7, wgl = bid >> 3;            // 32 blocks per XCD
    int mt = ((xcd & 3) << 2) + (wgl >> 3);       // 0..15
    int nt = ((xcd >> 2) << 3) + (wgl & 7);       // 0..15
    int m0 = mt << 8, n0 = nt * 192;

    int arow = t >> 1, akh = t & 1;               // A staging: thread -> (row, k-half)

    f32x4 acc[8][3];
    #pragma unroll
    for (int i = 0; i < 8; i++)
        #pragma unroll
        for (int j = 0; j < 3; j++) acc[i][j] = (f32x4){0.f, 0.f, 0.f, 0.f};

    #define QSTG_B(kt_, buf_)                                                                    \
        {                                                                                        \
            _Pragma("unroll")                                                                    \
            for (int u = 0; u < 3; u++) {                                                        \
                int L = t * 16 + u * 8192;                                                       \
                int row = L >> 7, gI = (L >> 4) & 7, gp = gI ^ (row & 7);                        \
                __builtin_amdgcn_global_load_lds(                                                \
                    (const AS1 void*)(Bt + (size_t)(n0 + row) * 1024 + (kt_) * 64 + gp * 8),     \
                    (AS3 void*)&Bs[buf_][L >> 1], 16, 0, 0);                                     \
            }                                                                                    \
        }

    #define ALOAD(kt_, av_)                                                                      \
        {                                                                                        \
            const float4* s4 = (const float4*)(A32 + (size_t)(m0 + arow) * 1024 + (kt_) * 64 + akh * 32); \
            _Pragma("unroll")                                                                    \
            for (int j = 0; j < 8; j++) av_[j] = s4[j];                                          \
        }

    #define AWRITE(av_, buf_)                                                                    \
        {                                                                                        \
            _Pragma("unroll")                                                                    \
            for (int j = 0; j < 4; j++) {                                                        \
                u32x4 wv;                                                                        \
                wv[0] = pkrne(av_[2 * j].x, av_[2 * j].y);                                       \
                wv[1] = pkrne(av_[2 * j].z, av_[2 * j].w);                                       \
                wv[2] = pkrne(av_[2 * j + 1].x, av_[2 * j + 1].y);                               \
                wv[3] = pkrne(av_[2 * j + 1].z, av_[2 * j + 1].w);                               \
                *(u32x4*)((char*)&As[buf_][0] + arow * 128 + ((((akh << 2) + j) ^ (arow & 7)) << 4)) = wv; \
            }                                                                                    \
        }

    // prologue: stage tile 0
    {
        float4 av0[8];
        ALOAD(0, av0);
        QSTG_B(0, 0);
        AWRITE(av0, 0);
    }
    __syncthreads();

    #pragma unroll 2
    for (int kt = 0; kt < 16; kt++) {
        const int c = kt & 1;
        float4 av[8];
        if (kt < 15) {
            ALOAD(kt + 1, av);
            QSTG_B(kt + 1, c ^ 1);
        }

        #pragma unroll
        for (int ks = 0; ks < 2; ks++) {
            short8 af[8], bfr[3];
            int cb = ((ks << 2) + g) << 4;        // byte offset of k-chunk in row
            #pragma unroll
            for (int mf = 0; mf < 8; mf++) {
                int row = (wr << 7) + (mf << 4) + ln;
                af[mf] = *(const short8*)((const char*)&As[c][0] + row * 128 + (cb ^ ((row & 7) << 4)));
            }
            #pragma unroll
            for (int nf = 0; nf < 3; nf++) {
                int row = wc * 48 + (nf << 4) + ln;
                bfr[nf] = *(const short8*)((const char*)&Bs[c][0] + row * 128 + (cb ^ ((row & 7) << 4)));
            }
            #pragma unroll
            for (int mf = 0; mf < 8; mf++)
                #pragma unroll
                for (int nf = 0; nf < 3; nf++)
                    acc[mf][nf] = __builtin_amdgcn_mfma_f32_16x16x32_bf16(af[mf], bfr[nf], acc[mf][nf], 0, 0, 0);
        }

        if (kt < 15) AWRITE(av, c ^ 1);   // compiler inserts precise vmcnt before first cvt

        __syncthreads();   // publishes A ds_writes + drains B gll + LDS reads of c done
    }
    #undef QSTG_B
    #undef ALOAD
    #undef AWRITE

    // epilogue: C/D layout col = lane&15, row = 4*(lane>>4)+r
    #pragma unroll
    for (int mf = 0; mf < 8; mf++)
        #pragma unroll
        for (int nf = 0; nf < 3; nf++) {
            int mb = m0 + (wr << 7) + (mf << 4) + (g << 2);
            int n = n0 + wc * 48 + (nf << 4) + ln;
            int j = n >> 10, col = n & 1023;
            int h = col >> 6, dk = col & 63;
            int b = mb >> 10, s = mb & 1023;
            if (j == 2) {
                ushort4 pk;
                pk.x = f2bf(acc[mf][nf][0]); pk.y = f2bf(acc[mf][nf][1]);
                pk.z = f2bf(acc[mf][nf][2]); pk.w = f2bf(acc[mf][nf][3]);
                *(ushort4*)(ov + ((size_t)(((b << 4) + h) * 64 + dk)) * 1024 + s) = pk;
            } else {
                u16* dst = (j == 0) ? oq : ok;
                #pragma unroll
                for (int r = 0; r < 4; r++)
                    dst[((size_t)(((b << 4) + h) * 1024 + s + r)) * 64 + dk] = f2bf(acc[mf][nf][r]);
            }
        }
}

// ---------------------------------------------------------------- output GEMM, 128x128 tile,
// 2-phase dbuf + chunk-swizzled LDS (r5-proven structure). grid = 256 (1 block/CU).
__global__ __launch_bounds__(256) void k_gemm_out(const u16* __restrict__ A, const u16* __restrict__ Bt,
                                                  float* __restrict__ outf) {
    const int K = 1024, N = 1024;
    __shared__ __align__(16) u16 As[2][8192];
    __shared__ __align__(16) u16 Bs[2][8192];
    int t = threadIdx.x, lane = t & 63, wave = t >> 6;
    int bid = blockIdx.y * 8 + blockIdx.x;
    int sbid = (bid & 7) * 32 + (bid >> 3);       // XCD-bijective (256 blocks)
    int m0 = (sbid >> 3) << 7, n0 = (sbid & 7) << 7;
    int wm = (wave >> 1) << 6, wn = (wave & 1) << 6;
    int g = lane >> 4, ln = lane & 15;
    f32x4 acc[4][4];
    #pragma unroll
    for (int i = 0; i < 4; i++)
        #pragma unroll
        for (int j = 0; j < 4; j++) acc[i][j] = (f32x4){0.f, 0.f, 0.f, 0.f};

    int schunk = ((lane & 3) ^ ((lane >> 3) & 3)) << 3;
    const u16* gA = A + (size_t)(m0 + wave * 16 + (lane >> 2)) * K + schunk;
    const u16* gB = Bt + (size_t)(n0 + wave * 16 + (lane >> 2)) * K + schunk;
    int ldsOff = wave * 512;

    #define GSTAGE(k0_, buf_)                                                                          \
        {                                                                                              \
            __builtin_amdgcn_global_load_lds((const AS1 void*)(gA + (k0_)),                            \
                                             (AS3 void*)&As[buf_][ldsOff], 16, 0, 0);                  \
            __builtin_amdgcn_global_load_lds((const AS1 void*)(gA + 64 * K + (k0_)),                   \
                                             (AS3 void*)&As[buf_][ldsOff + 2048], 16, 0, 0);           \
            __builtin_amdgcn_global_load_lds((const AS1 void*)(gB + (k0_)),                            \
                                             (AS3 void*)&Bs[buf_][ldsOff], 16, 0, 0);                  \
            __builtin_amdgcn_global_load_lds((const AS1 void*)(gB + 64 * K + (k0_)),                   \
                                             (AS3 void*)&Bs[buf_][ldsOff + 2048], 16, 0, 0);           \
        }

    GSTAGE(0, 0);
    __syncthreads();

    int rchunk = (g ^ ((ln >> 1) & 3)) << 3;

    #pragma unroll 2
    for (int kb = 0; kb < 32; kb++) {
        const int cur = kb & 1;
        if (kb < 31) GSTAGE((kb + 1) * 32, cur ^ 1);

        short8 af[4], bfr[4];
        #pragma unroll
        for (int fm = 0; fm < 4; fm++)
            af[fm] = *(const short8*)&As[cur][(wm + (fm << 4) + ln) * 32 + rchunk];
        #pragma unroll
        for (int fn = 0; fn < 4; fn++)
            bfr[fn] = *(const short8*)&Bs[cur][(wn + (fn << 4) + ln) * 32 + rchunk];
        #pragma unroll
        for (int fm = 0; fm < 4; fm++)
            #pragma unroll
            for (int fn = 0; fn < 4; fn++)
                acc[fm][fn] = __builtin_amdgcn_mfma_f32_16x16x32_bf16(af[fm], bfr[fn], acc[fm][fn], 0, 0, 0);

        __syncthreads();
    }

    #pragma unroll
    for (int fm = 0; fm < 4; fm++)
        #pragma unroll
        for (int fn = 0; fn < 4; fn++) {
            int mb = m0 + wm + (fm << 4) + (g << 2);
            int n = n0 + wn + (fn << 4) + ln;
            #pragma unroll
            for (int r = 0; r < 4; r++)
                outf[(size_t)(mb + r) * N + n] = acc[fm][fn][r];
        }
    #undef GSTAGE
}

// ---------------------------------------------------------------- flash attention (swapped QK^T,
// in-register P via permlane32_swap). grid = 512, block 256 (4 waves x 32 q), KV-block 64.
__global__ __launch_bounds__(256, 2) void k_attn(const u16* __restrict__ Qg, const u16* __restrict__ Kg,
                                                 const u16* __restrict__ Vtg, const float* __restrict__ bias2,
                                                 u16* __restrict__ attn_out) {
    __shared__ __align__(16) u16 Ks[2][64 * 64];
    __shared__ __align__(16) u16 Vts[2][64 * 64];
    __shared__ __align__(16) float blds4[4][1160];   // stride 1160: bank term uniform 2-way

    int t = threadIdx.x, lane = t & 63, w = t >> 6;
    int bid = blockIdx.x;
    int sid = (bid & 7) * 64 + (bid >> 3);          // XCD-aware swizzle
    int qb = sid & 7, h = (sid >> 3) & 15, b = sid >> 7;
    int q0 = qb << 7;
    const u16* Qh = Qg + ((size_t)(((b << 4) + h) * 1024 + q0)) * 64;
    const u16* Kh = Kg + (size_t)(((b << 4) + h)) * 1024 * 64;
    const u16* Vth = Vtg + (size_t)(((b << 4) + h)) * 64 * 1024;
    const float* bh = bias2 + (h << 11);

    int g = lane >> 4, ln = lane & 15;
    int lnk = (ln & 3) | ((ln & 4) << 1) | ((ln & 8) >> 1);   // kappa(ln): A-row -> K-seq remap
    int kbq = ((g & 1) << 3) | ((g >> 1) << 2);               // kappa base for D-rows 4g+r

    // Q fragments direct from global
    short8 qf[2][2];
    #pragma unroll
    for (int fm = 0; fm < 2; fm++)
        #pragma unroll
        for (int kh = 0; kh < 2; kh++)
            qf[fm][kh] = *(const short8*)(Qh + (size_t)(w * 32 + fm * 16 + ln) * 64 + kh * 32 + g * 8);

    // bias window, replicated x4 with element shifts for aligned float4 loads
    int w0 = 896 - q0;
    for (int i = t; i < 1152; i += 256) {
        float v = bh[w0 + i];
        #pragma unroll
        for (int a2 = 0; a2 < 4; a2++) { int x = i - a2; if (x >= 0) blds4[a2][x] = v; }
    }
    float b_hi = bh[1023 + 256];   // saturated bucket, rel >= 91
    float b_lo = bh[1023 - 256];   // saturated bucket, rel <= -91
    int aRep = (3 - ln) & 3;
    const float* repB = &blds4[aRep][0];

    #define STAGE(kb_, buf_)                                                                     \
        {                                                                                        \
            _Pragma("unroll")                                                                    \
            for (int r2 = 0; r2 < 2; r2++) {                                                     \
                int L = t * 16 + r2 * 4096;                                                      \
                int row = L >> 7, gI = (L >> 4) & 7, gp = gI ^ (row & 7);                        \
                __builtin_amdgcn_global_load_lds(                                                \
                    (const AS1 void*)(Kh + (size_t)((kb_) * 64 + row) * 64 + gp * 8),            \
                    (AS3 void*)&Ks[buf_][L >> 1], 16, 0, 0);                                     \
                __builtin_amdgcn_global_load_lds(                                                \
                    (const AS1 void*)(Vth + (size_t)row * 1024 + (kb_) * 64 + gp * 8),           \
                    (AS3 void*)&Vts[buf_][L >> 1], 16, 0, 0);                                    \
            }                                                                                    \
        }

    STAGE(0, 0);
    __syncthreads();

    float psum[2] = {0.f, 0.f};
    f32x4 o[2][4];
    #pragma unroll
    for (int fm = 0; fm < 2; fm++)
        #pragma unroll
        for (int dn = 0; dn < 4; dn++) o[fm][dn] = (f32x4){0.f, 0.f, 0.f, 0.f};

    #pragma unroll 2
    for (int kb = 0; kb < 16; kb++) {
        const int cur = kb & 1;
        if (kb < 15) STAGE(kb + 1, cur ^ 1);

        // ---- QK^T swapped + kappa row remap: s[fm][fn][r] = score(k = 64kb+16fn+kbq+r, q = 16fm+ln)
        f32x4 s[2][4];
        __builtin_amdgcn_s_setprio(1);
        #pragma unroll
        for (int fn = 0; fn < 4; fn++) {
            int row = (fn << 4) + lnk;
            short8 kf0 = *(const short8*)((const char*)Ks[cur] + row * 128 + (((g << 4) + 0)  ^ ((row & 7) << 4)));
            short8 kf1 = *(const short8*)((const char*)Ks[cur] + row * 128 + (((g << 4) + 64) ^ ((row & 7) << 4)));
            #pragma unroll
            for (int fm = 0; fm < 2; fm++) {
                f32x4 a = (f32x4){0.f, 0.f, 0.f, 0.f};
                a = __builtin_amdgcn_mfma_f32_16x16x32_bf16(kf0, qf[fm][0], a, 0, 0, 0);
                a = __builtin_amdgcn_mfma_f32_16x16x32_bf16(kf1, qf[fm][1], a, 0, 0, 0);
                s[fm][fn] = a;
            }
        }
        __builtin_amdgcn_s_setprio(0);

        // ---- softmax: p = exp2(s*log2e + bias); pack per quadrant into registers
        int d0 = 64 * kb - q0 - 32 * w;                     // k0 - q_wave_base
        int ibase = 64 * kb - 32 * w + 127 + kbq - ln;      // bias local index, r=0
        bool fast = (d0 >= 122) || (d0 <= -154);            // whole tile saturated
        float bu = d0 > 0 ? b_hi : b_lo;
        unsigned Px[2][4], Py[2][4];
        #pragma unroll
        for (int fm = 0; fm < 2; fm++)
            #pragma unroll
            for (int fn = 0; fn < 4; fn++) {
                f32x4 sv = s[fm][fn];
                float b0, b1, b2v, b3;
                if (fast) { b0 = b1 = b2v = b3 = bu; }
                else {
                    float4 bb = *(const float4*)(repB + (ibase + 16 * fn - 16 * fm - aRep));
                    b0 = bb.x; b1 = bb.y; b2v = bb.z; b3 = bb.w;
                }
                float p0 = EXP2(fmaf(sv[0], LOG2E, b0));
                float p1 = EXP2(fmaf(sv[1], LOG2E, b1));
                float p2 = EXP2(fmaf(sv[2], LOG2E, b2v));
                float p3 = EXP2(fmaf(sv[3], LOG2E, b3));
                psum[fm] += (p0 + p1) + (p2 + p3);
                Px[fm][fn] = pk2(p0, p1);
                Py[fm][fn] = pk2(p2, p3);
            }

        // ---- redistribute P in-register: per (fm,ks) two permlane32_swap give all 4 A-words
        short8 pa[2][2];
        #pragma unroll
        for (int fm = 0; fm < 2; fm++)
            #pragma unroll
            for (int ks = 0; ks < 2; ks++) {
                unsigned w0r = Px[fm][2 * ks], w2r = Px[fm][2 * ks + 1];
                unsigned w1r = Py[fm][2 * ks], w3r = Py[fm][2 * ks + 1];
                asm volatile("s_nop 1\n\tv_permlane32_swap_b32 %0, %1" : "+v"(w0r), "+v"(w2r));
                asm volatile("s_nop 1\n\tv_permlane32_swap_b32 %0, %1" : "+v"(w1r), "+v"(w3r));
                u32x4 tv; tv[0] = w0r; tv[1] = w1r; tv[2] = w2r; tv[3] = w3r;
                pa[fm][ks] = __builtin_bit_cast(short8, tv);
            }

        // ---- PV
        __builtin_amdgcn_s_setprio(1);
        #pragma unroll
        for (int dn = 0; dn < 4; dn++) {
            int vrow = (dn << 4) + ln;
            short8 vb0 = *(const short8*)((const char*)Vts[cur] + vrow * 128 + (((g << 4) + 0)  ^ ((vrow & 7) << 4)));
            short8 vb1 = *(const short8*)((const char*)Vts[cur] + vrow * 128 + (((g << 4) + 64) ^ ((vrow & 7) << 4)));
            #pragma unroll
            for (int fm = 0; fm < 2; fm++) {
                f32x4 a = o[fm][dn];
                a = __builtin_amdgcn_mfma_f32_16x16x32_bf16(pa[fm][0], vb0, a, 0, 0, 0);
                a = __builtin_amdgcn_mfma_f32_16x16x32_bf16(pa[fm][1], vb1, a, 0, 0, 0);
                o[fm][dn] = a;
            }
        }
        __builtin_amdgcn_s_setprio(0);

        __syncthreads();
    }

    // ---- finalize
    float linv[2][4];
    #pragma unroll
    for (int fm = 0; fm < 2; fm++) {
        float v = psum[fm];
        v += __shfl_xor(v, 16);
        v += __shfl_xor(v, 32);
        float inv = 1.0f / v;
        #pragma unroll
        for (int r = 0; r < 4; r++)
            linv[fm][r] = __shfl(inv, 4 * g + r);
    }
    #pragma unroll
    for (int fm = 0; fm < 2; fm++)
        #pragma unroll
        for (int dn = 0; dn < 4; dn++)
            #pragma unroll
            for (int r = 0; r < 4; r++) {
                int srow = q0 + 32 * w + 16 * fm + (g << 2) + r;
                int col = (h << 6) + (dn << 4) + ln;
                attn_out[((size_t)((b << 10) + srow) << 10) + col] = f2bf(o[fm][dn][r] * linv[fm][r]);
            }
}

// ---------------------------------------------------------------- launch
extern "C" void kernel_launch(void* const* d_in, const int* in_sizes, int n_in,
                              void* d_out, int out_size, void* d_ws, size_t ws_size,
                              hipStream_t stream) {
    const float* hidden = (const float*)d_in[0];
    const float* Wq = (const float*)d_in[1];
    const float* Wk = (const float*)d_in[2];
    const float* Wv = (const float*)d_in[3];
    const float* Wo = (const float*)d_in[4];
    const float* tbl = (const float*)d_in[5];

    u16* wt   = (u16*)d_ws;                       // 3072x1024 bf16
    u16* wot  = wt + 3072 * 1024;                 // 1024x1024 bf16
    u16* Qb   = wot + 1024 * 1024;                // [4][16][1024][64]
    u16* Kb   = Qb + 4 * 16 * 1024 * 64;          // [4][16][1024][64]
    u16* Vb   = Kb + 4 * 16 * 1024 * 64;          // [4][16][64][1024]  (transposed)
    u16* attn = Vb + 4 * 16 * 1024 * 64;          // 4096x1024 bf16
    float* bias = (float*)(attn + 4096 * 1024);   // [16][2048] f32 (folded)

    k_prep<<<dim3(32, 32, 5), 256, 0, stream>>>(Wq, Wk, Wv, Wo, tbl, wt, wot, bias);
    k_qkv<<<256, 512, 0, stream>>>(hidden, wt, Qb, Kb, Vb);
    k_attn<<<512, 256, 0, stream>>>(Qb, Kb, Vb, bias, attn);
    k_gemm_out<<<dim3(8, 32), 256, 0, stream>>>(attn, wot, (float*)d_out);
}

// Round 11
// 97.097 us; speedup vs baseline: 1.2227x; 1.2227x over previous
//
#include <hip/hip_runtime.h>
#include <hip/hip_bf16.h>

typedef __attribute__((ext_vector_type(8))) short short8;
typedef __attribute__((ext_vector_type(4))) float f32x4;
typedef __attribute__((ext_vector_type(4))) unsigned u32x4;
typedef unsigned short u16;

#define AS1 __attribute__((address_space(1)))
#define AS3 __attribute__((address_space(3)))

#define LOG2E 1.44269504088896f
#define FOLD_M 46.166241308446828f   // 32 * log2(e)
#define EXP2(x) __builtin_amdgcn_exp2f(x)

// fp32 -> bf16 round-to-nearest-even
__device__ __forceinline__ u16 f2bf(float f) {
    unsigned u = __builtin_bit_cast(unsigned, f);
    u += 0x7FFFu + ((u >> 16) & 1u);
    return (u16)(u >> 16);
}

// pack two f32 -> two bf16 in one u32 (round-half-up + v_perm) — P-matrix only
__device__ __forceinline__ unsigned pk2(float a, float b) {
    unsigned ua = __builtin_bit_cast(unsigned, a) + 0x8000u;
    unsigned ub = __builtin_bit_cast(unsigned, b) + 0x8000u;
    return __builtin_amdgcn_perm(ub, ua, 0x07060302);  // [ub.b3 ub.b2 ua.b3 ua.b2]
}

// ---------------------------------------------------------------- prep:
// z<4: weight transposes; z==4: folded bias table; z>=5: hidden f32->bf16 (4 slices)
__global__ __launch_bounds__(256) void k_prep(const float* __restrict__ hidden,
                                              const float* __restrict__ Wq, const float* __restrict__ Wk,
                                              const float* __restrict__ Wv, const float* __restrict__ Wo,
                                              const float* __restrict__ tbl,
                                              u16* __restrict__ hidb,
                                              u16* __restrict__ wt, u16* __restrict__ wot,
                                              float* __restrict__ bias2) {
    int z = blockIdx.z;
    if (z >= 5) {
        int i = ((z - 5) * 1024 + blockIdx.y * 32 + blockIdx.x) * 256 + threadIdx.x;
        float4 v = ((const float4*)hidden)[i];
        ushort4 o;
        o.x = f2bf(v.x); o.y = f2bf(v.y); o.z = f2bf(v.z); o.w = f2bf(v.w);
        ((ushort4*)hidb)[i] = o;
        return;
    }
    if (z == 4) {
        int idx = (blockIdx.y * 32 + blockIdx.x) * 256 + threadIdx.x;
        if (idx < 16 * 2048) {
            int r = idx & 2047, h = idx >> 11;
            int rel = r - 1023;
            int bucket = rel > 0 ? 16 : 0;
            int rp = rel < 0 ? -rel : rel;
            if (rp < 8) bucket += rp;
            else {
                int lb = 8 + (int)(log2f((float)rp * 0.125f) * 2.0f);
                bucket += (lb < 15 ? lb : 15);
            }
            bias2[idx] = tbl[bucket * 16 + h] * LOG2E - FOLD_M;
        }
        return;
    }
    const float* in = z == 0 ? Wq : z == 1 ? Wk : z == 2 ? Wv : Wo;
    u16* out = (z == 3) ? wot : wt + (size_t)z * 1024 * 1024;
    __shared__ float tile[32][33];
    int tx = threadIdx.x & 31, ty = threadIdx.x >> 5;
    int bx = blockIdx.x << 5, by = blockIdx.y << 5;
    #pragma unroll
    for (int j = 0; j < 32; j += 8)
        tile[ty + j][tx] = in[(size_t)(by + ty + j) * 1024 + bx + tx];
    __syncthreads();
    #pragma unroll
    for (int j = 0; j < 32; j += 8)
        out[(size_t)(bx + ty + j) * 1024 + by + tx] = f2bf(tile[tx][ty + j]);
}

// ---------------------------------------------------------------- QKV GEMM: 256x192 tile, 8 waves,
// BK=64, grid = 256 (exactly 1 block/CU). LDS 112 KB: 2-dbuf A[256][64] + B[192][64],
// rows XOR-swizzled (byte ^= (row&7)<<4), staged via global_load_lds (7 uniform loads/thread/step)
// with pre-swizzled global source. 2D XCD chunking (5 MB working set ~ L2-resident).
// Wave-tile 128x48. Epilogue scatters Q/K [B][H][S][64], Vt [B][H][64][S].
__global__ __launch_bounds__(512, 2) void k_qkv(const u16* __restrict__ A, const u16* __restrict__ Bt,
                                                u16* __restrict__ oq, u16* __restrict__ ok,
                                                u16* __restrict__ ov) {
    __shared__ __align__(16) u16 As[2][256 * 64];
    __shared__ __align__(16) u16 Bs[2][192 * 64];
    int t = threadIdx.x, lane = t & 63, wave = t >> 6;
    int g = lane >> 4, ln = lane & 15;
    int wr = wave >> 2, wc = wave & 3;            // 2M x 4N wave grid

    int bid = blockIdx.x;
    int xcd = bid & 7, wgl = bid >> 3;            // 32 blocks per XCD
    int mt = ((xcd & 3) << 2) + (wgl >> 3);       // 0..15
    int nt = ((xcd >> 2) << 3) + (wgl & 7);       // 0..15
    int m0 = mt << 8, n0 = nt * 192;

    f32x4 acc[8][3];
    #pragma unroll
    for (int i = 0; i < 8; i++)
        #pragma unroll
        for (int j = 0; j < 3; j++) acc[i][j] = (f32x4){0.f, 0.f, 0.f, 0.f};

    // staging: linear LDS dest; global source 16B-chunk pre-swizzled (gp = gI ^ (row&7))
    #define QSTG(kt_, buf_)                                                                      \
        {                                                                                        \
            _Pragma("unroll")                                                                    \
            for (int u = 0; u < 4; u++) {                                                        \
                int L = t * 16 + u * 8192;                                                       \
                int row = L >> 7, gI = (L >> 4) & 7, gp = gI ^ (row & 7);                        \
                __builtin_amdgcn_global_load_lds(                                                \
                    (const AS1 void*)(A + (size_t)(m0 + row) * 1024 + (kt_) * 64 + gp * 8),      \
                    (AS3 void*)&As[buf_][L >> 1], 16, 0, 0);                                     \
            }                                                                                    \
            _Pragma("unroll")                                                                    \
            for (int u = 0; u < 3; u++) {                                                        \
                int L = t * 16 + u * 8192;                                                       \
                int row = L >> 7, gI = (L >> 4) & 7, gp = gI ^ (row & 7);                        \
                __builtin_amdgcn_global_load_lds(                                                \
                    (const AS1 void*)(Bt + (size_t)(n0 + row) * 1024 + (kt_) * 64 + gp * 8),     \
                    (AS3 void*)&Bs[buf_][L >> 1], 16, 0, 0);                                     \
            }                                                                                    \
        }

    QSTG(0, 0);
    __syncthreads();

    #pragma unroll 2
    for (int kt = 0; kt < 16; kt++) {
        const int c = kt & 1;
        if (kt < 15) QSTG(kt + 1, c ^ 1);

        #pragma unroll
        for (int ks = 0; ks < 2; ks++) {
            short8 af[8], bfr[3];
            int cb = ((ks << 2) + g) << 4;        // byte offset of k-chunk in row
            #pragma unroll
            for (int mf = 0; mf < 8; mf++) {
                int row = (wr << 7) + (mf << 4) + ln;
                af[mf] = *(const short8*)((const char*)&As[c][0] + row * 128 + (cb ^ ((row & 7) << 4)));
            }
            #pragma unroll
            for (int nf = 0; nf < 3; nf++) {
                int row = wc * 48 + (nf << 4) + ln;
                bfr[nf] = *(const short8*)((const char*)&Bs[c][0] + row * 128 + (cb ^ ((row & 7) << 4)));
            }
            __builtin_amdgcn_s_setprio(1);
            #pragma unroll
            for (int mf = 0; mf < 8; mf++)
                #pragma unroll
                for (int nf = 0; nf < 3; nf++)
                    acc[mf][nf] = __builtin_amdgcn_mfma_f32_16x16x32_bf16(af[mf], bfr[nf], acc[mf][nf], 0, 0, 0);
            __builtin_amdgcn_s_setprio(0);
        }
        __syncthreads();   // drains vmcnt (next tile staged) + LDS reads of c done
    }
    #undef QSTG

    // epilogue: C/D layout col = lane&15, row = 4*(lane>>4)+r
    #pragma unroll
    for (int mf = 0; mf < 8; mf++)
        #pragma unroll
        for (int nf = 0; nf < 3; nf++) {
            int mb = m0 + (wr << 7) + (mf << 4) + (g << 2);
            int n = n0 + wc * 48 + (nf << 4) + ln;
            int j = n >> 10, col = n & 1023;
            int h = col >> 6, dk = col & 63;
            int b = mb >> 10, s = mb & 1023;
            if (j == 2) {
                ushort4 pk;
                pk.x = f2bf(acc[mf][nf][0]); pk.y = f2bf(acc[mf][nf][1]);
                pk.z = f2bf(acc[mf][nf][2]); pk.w = f2bf(acc[mf][nf][3]);
                *(ushort4*)(ov + ((size_t)(((b << 4) + h) * 64 + dk)) * 1024 + s) = pk;
            } else {
                u16* dst = (j == 0) ? oq : ok;
                #pragma unroll
                for (int r = 0; r < 4; r++)
                    dst[((size_t)(((b << 4) + h) * 1024 + s + r)) * 64 + dk] = f2bf(acc[mf][nf][r]);
            }
        }
}

// ---------------------------------------------------------------- output GEMM, 128x128 tile,
// 2-phase dbuf + chunk-swizzled LDS (r5-proven structure). grid = 256 (1 block/CU).
__global__ __launch_bounds__(256) void k_gemm_out(const u16* __restrict__ A, const u16* __restrict__ Bt,
                                                  float* __restrict__ outf) {
    const int K = 1024, N = 1024;
    __shared__ __align__(16) u16 As[2][8192];
    __shared__ __align__(16) u16 Bs[2][8192];
    int t = threadIdx.x, lane = t & 63, wave = t >> 6;
    int bid = blockIdx.y * 8 + blockIdx.x;
    int sbid = (bid & 7) * 32 + (bid >> 3);       // XCD-bijective (256 blocks)
    int m0 = (sbid >> 3) << 7, n0 = (sbid & 7) << 7;
    int wm = (wave >> 1) << 6, wn = (wave & 1) << 6;
    int g = lane >> 4, ln = lane & 15;
    f32x4 acc[4][4];
    #pragma unroll
    for (int i = 0; i < 4; i++)
        #pragma unroll
        for (int j = 0; j < 4; j++) acc[i][j] = (f32x4){0.f, 0.f, 0.f, 0.f};

    int schunk = ((lane & 3) ^ ((lane >> 3) & 3)) << 3;
    const u16* gA = A + (size_t)(m0 + wave * 16 + (lane >> 2)) * K + schunk;
    const u16* gB = Bt + (size_t)(n0 + wave * 16 + (lane >> 2)) * K + schunk;
    int ldsOff = wave * 512;

    #define GSTAGE(k0_, buf_)                                                                          \
        {                                                                                              \
            __builtin_amdgcn_global_load_lds((const AS1 void*)(gA + (k0_)),                            \
                                             (AS3 void*)&As[buf_][ldsOff], 16, 0, 0);                  \
            __builtin_amdgcn_global_load_lds((const AS1 void*)(gA + 64 * K + (k0_)),                   \
                                             (AS3 void*)&As[buf_][ldsOff + 2048], 16, 0, 0);           \
            __builtin_amdgcn_global_load_lds((const AS1 void*)(gB + (k0_)),                            \
                                             (AS3 void*)&Bs[buf_][ldsOff], 16, 0, 0);                  \
            __builtin_amdgcn_global_load_lds((const AS1 void*)(gB + 64 * K + (k0_)),                   \
                                             (AS3 void*)&Bs[buf_][ldsOff + 2048], 16, 0, 0);           \
        }

    GSTAGE(0, 0);
    __syncthreads();

    int rchunk = (g ^ ((ln >> 1) & 3)) << 3;

    #pragma unroll 2
    for (int kb = 0; kb < 32; kb++) {
        const int cur = kb & 1;
        if (kb < 31) GSTAGE((kb + 1) * 32, cur ^ 1);

        short8 af[4], bfr[4];
        #pragma unroll
        for (int fm = 0; fm < 4; fm++)
            af[fm] = *(const short8*)&As[cur][(wm + (fm << 4) + ln) * 32 + rchunk];
        #pragma unroll
        for (int fn = 0; fn < 4; fn++)
            bfr[fn] = *(const short8*)&Bs[cur][(wn + (fn << 4) + ln) * 32 + rchunk];
        #pragma unroll
        for (int fm = 0; fm < 4; fm++)
            #pragma unroll
            for (int fn = 0; fn < 4; fn++)
                acc[fm][fn] = __builtin_amdgcn_mfma_f32_16x16x32_bf16(af[fm], bfr[fn], acc[fm][fn], 0, 0, 0);

        __syncthreads();
    }

    #pragma unroll
    for (int fm = 0; fm < 4; fm++)
        #pragma unroll
        for (int fn = 0; fn < 4; fn++) {
            int mb = m0 + wm + (fm << 4) + (g << 2);
            int n = n0 + wn + (fn << 4) + ln;
            #pragma unroll
            for (int r = 0; r < 4; r++)
                outf[(size_t)(mb + r) * N + n] = acc[fm][fn][r];
        }
    #undef GSTAGE
}

// ---------------------------------------------------------------- flash attention (swapped QK^T,
// in-register P via permlane32_swap). grid = 512, block 256 (4 waves x 32 q), KV-block 64.
__global__ __launch_bounds__(256, 2) void k_attn(const u16* __restrict__ Qg, const u16* __restrict__ Kg,
                                                 const u16* __restrict__ Vtg, const float* __restrict__ bias2,
                                                 u16* __restrict__ attn_out) {
    __shared__ __align__(16) u16 Ks[2][64 * 64];
    __shared__ __align__(16) u16 Vts[2][64 * 64];
    __shared__ __align__(16) float blds4[4][1160];   // stride 1160: bank term uniform 2-way

    int t = threadIdx.x, lane = t & 63, w = t >> 6;
    int bid = blockIdx.x;
    int sid = (bid & 7) * 64 + (bid >> 3);          // XCD-aware swizzle
    int qb = sid & 7, h = (sid >> 3) & 15, b = sid >> 7;
    int q0 = qb << 7;
    const u16* Qh = Qg + ((size_t)(((b << 4) + h) * 1024 + q0)) * 64;
    const u16* Kh = Kg + (size_t)(((b << 4) + h)) * 1024 * 64;
    const u16* Vth = Vtg + (size_t)(((b << 4) + h)) * 64 * 1024;
    const float* bh = bias2 + (h << 11);

    int g = lane >> 4, ln = lane & 15;
    int lnk = (ln & 3) | ((ln & 4) << 1) | ((ln & 8) >> 1);   // kappa(ln): A-row -> K-seq remap
    int kbq = ((g & 1) << 3) | ((g >> 1) << 2);               // kappa base for D-rows 4g+r

    // Q fragments direct from global
    short8 qf[2][2];
    #pragma unroll
    for (int fm = 0; fm < 2; fm++)
        #pragma unroll
        for (int kh = 0; kh < 2; kh++)
            qf[fm][kh] = *(const short8*)(Qh + (size_t)(w * 32 + fm * 16 + ln) * 64 + kh * 32 + g * 8);

    // bias window, replicated x4 with element shifts for aligned float4 loads
    int w0 = 896 - q0;
    for (int i = t; i < 1152; i += 256) {
        float v = bh[w0 + i];
        #pragma unroll
        for (int a2 = 0; a2 < 4; a2++) { int x = i - a2; if (x >= 0) blds4[a2][x] = v; }
    }
    float b_hi = bh[1023 + 256];   // saturated bucket, rel >= 91
    float b_lo = bh[1023 - 256];   // saturated bucket, rel <= -91
    int aRep = (3 - ln) & 3;
    const float* repB = &blds4[aRep][0];

    #define STAGE(kb_, buf_)                                                                     \
        {                                                                                        \
            _Pragma("unroll")                                                                    \
            for (int r2 = 0; r2 < 2; r2++) {                                                     \
                int L = t * 16 + r2 * 4096;                                                      \
                int row = L >> 7, gI = (L >> 4) & 7, gp = gI ^ (row & 7);                        \
                __builtin_amdgcn_global_load_lds(                                                \
                    (const AS1 void*)(Kh + (size_t)((kb_) * 64 + row) * 64 + gp * 8),            \
                    (AS3 void*)&Ks[buf_][L >> 1], 16, 0, 0);                                     \
                __builtin_amdgcn_global_load_lds(                                                \
                    (const AS1 void*)(Vth + (size_t)row * 1024 + (kb_) * 64 + gp * 8),           \
                    (AS3 void*)&Vts[buf_][L >> 1], 16, 0, 0);                                    \
            }                                                                                    \
        }

    STAGE(0, 0);
    __syncthreads();

    float psum[2] = {0.f, 0.f};
    f32x4 o[2][4];
    #pragma unroll
    for (int fm = 0; fm < 2; fm++)
        #pragma unroll
        for (int dn = 0; dn < 4; dn++) o[fm][dn] = (f32x4){0.f, 0.f, 0.f, 0.f};

    #pragma unroll 2
    for (int kb = 0; kb < 16; kb++) {
        const int cur = kb & 1;
        if (kb < 15) STAGE(kb + 1, cur ^ 1);

        // ---- QK^T swapped + kappa row remap: s[fm][fn][r] = score(k = 64kb+16fn+kbq+r, q = 16fm+ln)
        f32x4 s[2][4];
        __builtin_amdgcn_s_setprio(1);
        #pragma unroll
        for (int fn = 0; fn < 4; fn++) {
            int row = (fn << 4) + lnk;
            short8 kf0 = *(const short8*)((const char*)Ks[cur] + row * 128 + (((g << 4) + 0)  ^ ((row & 7) << 4)));
            short8 kf1 = *(const short8*)((const char*)Ks[cur] + row * 128 + (((g << 4) + 64) ^ ((row & 7) << 4)));
            #pragma unroll
            for (int fm = 0; fm < 2; fm++) {
                f32x4 a = (f32x4){0.f, 0.f, 0.f, 0.f};
                a = __builtin_amdgcn_mfma_f32_16x16x32_bf16(kf0, qf[fm][0], a, 0, 0, 0);
                a = __builtin_amdgcn_mfma_f32_16x16x32_bf16(kf1, qf[fm][1], a, 0, 0, 0);
                s[fm][fn] = a;
            }
        }
        __builtin_amdgcn_s_setprio(0);

        // ---- softmax: p = exp2(s*log2e + bias); pack per quadrant into registers
        int d0 = 64 * kb - q0 - 32 * w;                     // k0 - q_wave_base
        int ibase = 64 * kb - 32 * w + 127 + kbq - ln;      // bias local index, r=0
        bool fast = (d0 >= 122) || (d0 <= -154);            // whole tile saturated
        float bu = d0 > 0 ? b_hi : b_lo;
        unsigned Px[2][4], Py[2][4];
        #pragma unroll
        for (int fm = 0; fm < 2; fm++)
            #pragma unroll
            for (int fn = 0; fn < 4; fn++) {
                f32x4 sv = s[fm][fn];
                float b0, b1, b2v, b3;
                if (fast) { b0 = b1 = b2v = b3 = bu; }
                else {
                    float4 bb = *(const float4*)(repB + (ibase + 16 * fn - 16 * fm - aRep));
                    b0 = bb.x; b1 = bb.y; b2v = bb.z; b3 = bb.w;
                }
                float p0 = EXP2(fmaf(sv[0], LOG2E, b0));
                float p1 = EXP2(fmaf(sv[1], LOG2E, b1));
                float p2 = EXP2(fmaf(sv[2], LOG2E, b2v));
                float p3 = EXP2(fmaf(sv[3], LOG2E, b3));
                psum[fm] += (p0 + p1) + (p2 + p3);
                Px[fm][fn] = pk2(p0, p1);
                Py[fm][fn] = pk2(p2, p3);
            }

        // ---- redistribute P in-register: per (fm,ks) two permlane32_swap give all 4 A-words
        short8 pa[2][2];
        #pragma unroll
        for (int fm = 0; fm < 2; fm++)
            #pragma unroll
            for (int ks = 0; ks < 2; ks++) {
                unsigned w0r = Px[fm][2 * ks], w2r = Px[fm][2 * ks + 1];
                unsigned w1r = Py[fm][2 * ks], w3r = Py[fm][2 * ks + 1];
                asm volatile("s_nop 1\n\tv_permlane32_swap_b32 %0, %1" : "+v"(w0r), "+v"(w2r));
                asm volatile("s_nop 1\n\tv_permlane32_swap_b32 %0, %1" : "+v"(w1r), "+v"(w3r));
                u32x4 tv; tv[0] = w0r; tv[1] = w1r; tv[2] = w2r; tv[3] = w3r;
                pa[fm][ks] = __builtin_bit_cast(short8, tv);
            }

        // ---- PV
        __builtin_amdgcn_s_setprio(1);
        #pragma unroll
        for (int dn = 0; dn < 4; dn++) {
            int vrow = (dn << 4) + ln;
            short8 vb0 = *(const short8*)((const char*)Vts[cur] + vrow * 128 + (((g << 4) + 0)  ^ ((vrow & 7) << 4)));
            short8 vb1 = *(const short8*)((const char*)Vts[cur] + vrow * 128 + (((g << 4) + 64) ^ ((vrow & 7) << 4)));
            #pragma unroll
            for (int fm = 0; fm < 2; fm++) {
                f32x4 a = o[fm][dn];
                a = __builtin_amdgcn_mfma_f32_16x16x32_bf16(pa[fm][0], vb0, a, 0, 0, 0);
                a = __builtin_amdgcn_mfma_f32_16x16x32_bf16(pa[fm][1], vb1, a, 0, 0, 0);
                o[fm][dn] = a;
            }
        }
        __builtin_amdgcn_s_setprio(0);

        __syncthreads();
    }

    // ---- finalize
    float linv[2][4];
    #pragma unroll
    for (int fm = 0; fm < 2; fm++) {
        float v = psum[fm];
        v += __shfl_xor(v, 16);
        v += __shfl_xor(v, 32);
        float inv = 1.0f / v;
        #pragma unroll
        for (int r = 0; r < 4; r++)
            linv[fm][r] = __shfl(inv, 4 * g + r);
    }
    #pragma unroll
    for (int fm = 0; fm < 2; fm++)
        #pragma unroll
        for (int dn = 0; dn < 4; dn++)
            #pragma unroll
            for (int r = 0; r < 4; r++) {
                int srow = q0 + 32 * w + 16 * fm + (g << 2) + r;
                int col = (h << 6) + (dn << 4) + ln;
                attn_out[((size_t)((b << 10) + srow) << 10) + col] = f2bf(o[fm][dn][r] * linv[fm][r]);
            }
}

// ---------------------------------------------------------------- launch
extern "C" void kernel_launch(void* const* d_in, const int* in_sizes, int n_in,
                              void* d_out, int out_size, void* d_ws, size_t ws_size,
                              hipStream_t stream) {
    const float* hidden = (const float*)d_in[0];
    const float* Wq = (const float*)d_in[1];
    const float* Wk = (const float*)d_in[2];
    const float* Wv = (const float*)d_in[3];
    const float* Wo = (const float*)d_in[4];
    const float* tbl = (const float*)d_in[5];

    u16* hidb = (u16*)d_ws;                       // 4096x1024 bf16
    u16* wt   = hidb + 4096 * 1024;               // 3072x1024 bf16
    u16* wot  = wt + 3072 * 1024;                 // 1024x1024 bf16
    u16* Qb   = wot + 1024 * 1024;                // [4][16][1024][64]
    u16* Kb   = Qb + 4 * 16 * 1024 * 64;          // [4][16][1024][64]
    u16* Vb   = Kb + 4 * 16 * 1024 * 64;          // [4][16][64][1024]  (transposed)
    u16* attn = Vb + 4 * 16 * 1024 * 64;          // 4096x1024 bf16
    float* bias = (float*)(attn + 4096 * 1024);   // [16][2048] f32 (folded)

    k_prep<<<dim3(32, 32, 9), 256, 0, stream>>>(hidden, Wq, Wk, Wv, Wo, tbl, hidb, wt, wot, bias);
    k_qkv<<<256, 512, 0, stream>>>(hidb, wt, Qb, Kb, Vb);
    k_attn<<<512, 256, 0, stream>>>(Qb, Kb, Vb, bias, attn);
    k_gemm_out<<<dim3(8, 32), 256, 0, stream>>>(attn, wot, (float*)d_out);
}

// Round 12
// 93.727 us; speedup vs baseline: 1.2666x; 1.0360x over previous
//
#include <hip/hip_runtime.h>
#include <hip/hip_bf16.h>

typedef __attribute__((ext_vector_type(8))) short short8;
typedef __attribute__((ext_vector_type(4))) float f32x4;
typedef __attribute__((ext_vector_type(4))) unsigned u32x4;
typedef unsigned short u16;

#define AS1 __attribute__((address_space(1)))
#define AS3 __attribute__((address_space(3)))

#define LOG2E 1.44269504088896f
#define FOLD_M 46.166241308446828f   // 32 * log2(e)
#define EXP2(x) __builtin_amdgcn_exp2f(x)
#define WAITV(n) asm volatile("s_waitcnt vmcnt(" #n ")" ::: "memory")
#define BAR() __builtin_amdgcn_s_barrier()

// fp32 -> bf16 round-to-nearest-even
__device__ __forceinline__ u16 f2bf(float f) {
    unsigned u = __builtin_bit_cast(unsigned, f);
    u += 0x7FFFu + ((u >> 16) & 1u);
    return (u16)(u >> 16);
}

// pack two f32 -> two bf16 in one u32 (round-half-up + v_perm) — P-matrix only
__device__ __forceinline__ unsigned pk2(float a, float b) {
    unsigned ua = __builtin_bit_cast(unsigned, a) + 0x8000u;
    unsigned ub = __builtin_bit_cast(unsigned, b) + 0x8000u;
    return __builtin_amdgcn_perm(ub, ua, 0x07060302);  // [ub.b3 ub.b2 ua.b3 ua.b2]
}

// ---------------------------------------------------------------- prep:
// z<4: weight transposes; z==4: folded bias table; z>=5: hidden f32->bf16 (4 slices)
__global__ __launch_bounds__(256) void k_prep(const float* __restrict__ hidden,
                                              const float* __restrict__ Wq, const float* __restrict__ Wk,
                                              const float* __restrict__ Wv, const float* __restrict__ Wo,
                                              const float* __restrict__ tbl,
                                              u16* __restrict__ hidb,
                                              u16* __restrict__ wt, u16* __restrict__ wot,
                                              float* __restrict__ bias2) {
    int z = blockIdx.z;
    if (z >= 5) {
        int i = ((z - 5) * 1024 + blockIdx.y * 32 + blockIdx.x) * 256 + threadIdx.x;
        float4 v = ((const float4*)hidden)[i];
        ushort4 o;
        o.x = f2bf(v.x); o.y = f2bf(v.y); o.z = f2bf(v.z); o.w = f2bf(v.w);
        ((ushort4*)hidb)[i] = o;
        return;
    }
    if (z == 4) {
        int idx = (blockIdx.y * 32 + blockIdx.x) * 256 + threadIdx.x;
        if (idx < 16 * 2048) {
            int r = idx & 2047, h = idx >> 11;
            int rel = r - 1023;
            int bucket = rel > 0 ? 16 : 0;
            int rp = rel < 0 ? -rel : rel;
            if (rp < 8) bucket += rp;
            else {
                int lb = 8 + (int)(log2f((float)rp * 0.125f) * 2.0f);
                bucket += (lb < 15 ? lb : 15);
            }
            bias2[idx] = tbl[bucket * 16 + h] * LOG2E - FOLD_M;
        }
        return;
    }
    const float* in = z == 0 ? Wq : z == 1 ? Wk : z == 2 ? Wv : Wo;
    u16* out = (z == 3) ? wot : wt + (size_t)z * 1024 * 1024;
    __shared__ float tile[32][33];
    int tx = threadIdx.x & 31, ty = threadIdx.x >> 5;
    int bx = blockIdx.x << 5, by = blockIdx.y << 5;
    #pragma unroll
    for (int j = 0; j < 32; j += 8)
        tile[ty + j][tx] = in[(size_t)(by + ty + j) * 1024 + bx + tx];
    __syncthreads();
    #pragma unroll
    for (int j = 0; j < 32; j += 8)
        out[(size_t)(bx + ty + j) * 1024 + by + tx] = f2bf(tile[tx][ty + j]);
}

// ---------------------------------------------------------------- QKV GEMM: 256x192 tile, 8 waves,
// BK=64, grid = 256 (1 block/CU). 2-dbuf, counted-vmcnt loop (no drain): issue stage(kt+1),
// WAITV(7) = wait only stage(kt) (issued one iter ago, ~free), raw barriers.
// LDS rows XOR-swizzled (byte ^= (row&7)<<4); staged via global_load_lds w/ pre-swizzled source.
__global__ __launch_bounds__(512, 2) void k_qkv(const u16* __restrict__ A, const u16* __restrict__ Bt,
                                                u16* __restrict__ oq, u16* __restrict__ ok,
                                                u16* __restrict__ ov) {
    __shared__ __align__(16) u16 As[2][256 * 64];
    __shared__ __align__(16) u16 Bs[2][192 * 64];
    int t = threadIdx.x, lane = t & 63, wave = t >> 6;
    int g = lane >> 4, ln = lane & 15;
    int wr = wave >> 2, wc = wave & 3;            // 2M x 4N wave grid

    int bid = blockIdx.x;
    int xcd = bid & 7, wgl = bid >> 3;            // 32 blocks per XCD
    int mt = ((xcd & 3) << 2) + (wgl >> 3);       // 0..15
    int nt = ((xcd >> 2) << 3) + (wgl & 7);       // 0..15
    int m0 = mt << 8, n0 = nt * 192;

    f32x4 acc[8][3];
    #pragma unroll
    for (int i = 0; i < 8; i++)
        #pragma unroll
        for (int j = 0; j < 3; j++) acc[i][j] = (f32x4){0.f, 0.f, 0.f, 0.f};

    // staging: linear LDS dest; global source 16B-chunk pre-swizzled (gp = gI ^ (row&7))
    #define QSTG(kt_, buf_)                                                                      \
        {                                                                                        \
            _Pragma("unroll")                                                                    \
            for (int u = 0; u < 4; u++) {                                                        \
                int L = t * 16 + u * 8192;                                                       \
                int row = L >> 7, gI = (L >> 4) & 7, gp = gI ^ (row & 7);                        \
                __builtin_amdgcn_global_load_lds(                                                \
                    (const AS1 void*)(A + (size_t)(m0 + row) * 1024 + (kt_) * 64 + gp * 8),      \
                    (AS3 void*)&As[buf_][L >> 1], 16, 0, 0);                                     \
            }                                                                                    \
            _Pragma("unroll")                                                                    \
            for (int u = 0; u < 3; u++) {                                                        \
                int L = t * 16 + u * 8192;                                                       \
                int row = L >> 7, gI = (L >> 4) & 7, gp = gI ^ (row & 7);                        \
                __builtin_amdgcn_global_load_lds(                                                \
                    (const AS1 void*)(Bt + (size_t)(n0 + row) * 1024 + (kt_) * 64 + gp * 8),     \
                    (AS3 void*)&Bs[buf_][L >> 1], 16, 0, 0);                                     \
            }                                                                                    \
        }

    QSTG(0, 0);

    #pragma unroll 2
    for (int kt = 0; kt < 16; kt++) {
        const int c = kt & 1;
        if (kt < 15) {
            QSTG(kt + 1, c ^ 1);
            WAITV(7);          // stage(kt) landed; stage(kt+1) stays in flight across the barrier
        } else {
            WAITV(0);
        }
        BAR();                 // publish stage(kt) block-wide

        #pragma unroll
        for (int ks = 0; ks < 2; ks++) {
            short8 af[8], bfr[3];
            int cb = ((ks << 2) + g) << 4;        // byte offset of k-chunk in row
            #pragma unroll
            for (int mf = 0; mf < 8; mf++) {
                int row = (wr << 7) + (mf << 4) + ln;
                af[mf] = *(const short8*)((const char*)&As[c][0] + row * 128 + (cb ^ ((row & 7) << 4)));
            }
            #pragma unroll
            for (int nf = 0; nf < 3; nf++) {
                int row = wc * 48 + (nf << 4) + ln;
                bfr[nf] = *(const short8*)((const char*)&Bs[c][0] + row * 128 + (cb ^ ((row & 7) << 4)));
            }
            #pragma unroll
            for (int mf = 0; mf < 8; mf++)
                #pragma unroll
                for (int nf = 0; nf < 3; nf++)
                    acc[mf][nf] = __builtin_amdgcn_mfma_f32_16x16x32_bf16(af[mf], bfr[nf], acc[mf][nf], 0, 0, 0);
        }
        BAR();                 // all reads of buf c done before next iter overwrites it
    }
    #undef QSTG

    // epilogue: C/D layout col = lane&15, row = 4*(lane>>4)+r
    #pragma unroll
    for (int mf = 0; mf < 8; mf++)
        #pragma unroll
        for (int nf = 0; nf < 3; nf++) {
            int mb = m0 + (wr << 7) + (mf << 4) + (g << 2);
            int n = n0 + wc * 48 + (nf << 4) + ln;
            int j = n >> 10, col = n & 1023;
            int h = col >> 6, dk = col & 63;
            int b = mb >> 10, s = mb & 1023;
            if (j == 2) {
                ushort4 pk;
                pk.x = f2bf(acc[mf][nf][0]); pk.y = f2bf(acc[mf][nf][1]);
                pk.z = f2bf(acc[mf][nf][2]); pk.w = f2bf(acc[mf][nf][3]);
                *(ushort4*)(ov + ((size_t)(((b << 4) + h) * 64 + dk)) * 1024 + s) = pk;
            } else {
                u16* dst = (j == 0) ? oq : ok;
                #pragma unroll
                for (int r = 0; r < 4; r++)
                    dst[((size_t)(((b << 4) + h) * 1024 + s + r)) * 64 + dk] = f2bf(acc[mf][nf][r]);
            }
        }
}

// ---------------------------------------------------------------- output GEMM, 128x128 tile,
// 2-dbuf + counted-vmcnt loop + chunk-swizzled LDS. grid = 256 (1 block/CU).
__global__ __launch_bounds__(256) void k_gemm_out(const u16* __restrict__ A, const u16* __restrict__ Bt,
                                                  float* __restrict__ outf) {
    const int K = 1024, N = 1024;
    __shared__ __align__(16) u16 As[2][8192];
    __shared__ __align__(16) u16 Bs[2][8192];
    int t = threadIdx.x, lane = t & 63, wave = t >> 6;
    int bid = blockIdx.y * 8 + blockIdx.x;
    int sbid = (bid & 7) * 32 + (bid >> 3);       // XCD-bijective (256 blocks)
    int m0 = (sbid >> 3) << 7, n0 = (sbid & 7) << 7;
    int wm = (wave >> 1) << 6, wn = (wave & 1) << 6;
    int g = lane >> 4, ln = lane & 15;
    f32x4 acc[4][4];
    #pragma unroll
    for (int i = 0; i < 4; i++)
        #pragma unroll
        for (int j = 0; j < 4; j++) acc[i][j] = (f32x4){0.f, 0.f, 0.f, 0.f};

    int schunk = ((lane & 3) ^ ((lane >> 3) & 3)) << 3;
    const u16* gA = A + (size_t)(m0 + wave * 16 + (lane >> 2)) * K + schunk;
    const u16* gB = Bt + (size_t)(n0 + wave * 16 + (lane >> 2)) * K + schunk;
    int ldsOff = wave * 512;

    #define GSTAGE(k0_, buf_)                                                                          \
        {                                                                                              \
            __builtin_amdgcn_global_load_lds((const AS1 void*)(gA + (k0_)),                            \
                                             (AS3 void*)&As[buf_][ldsOff], 16, 0, 0);                  \
            __builtin_amdgcn_global_load_lds((const AS1 void*)(gA + 64 * K + (k0_)),                   \
                                             (AS3 void*)&As[buf_][ldsOff + 2048], 16, 0, 0);           \
            __builtin_amdgcn_global_load_lds((const AS1 void*)(gB + (k0_)),                            \
                                             (AS3 void*)&Bs[buf_][ldsOff], 16, 0, 0);                  \
            __builtin_amdgcn_global_load_lds((const AS1 void*)(gB + 64 * K + (k0_)),                   \
                                             (AS3 void*)&Bs[buf_][ldsOff + 2048], 16, 0, 0);           \
        }

    GSTAGE(0, 0);

    int rchunk = (g ^ ((ln >> 1) & 3)) << 3;

    #pragma unroll 2
    for (int kb = 0; kb < 32; kb++) {
        const int cur = kb & 1;
        if (kb < 31) {
            GSTAGE((kb + 1) * 32, cur ^ 1);
            WAITV(4);
        } else {
            WAITV(0);
        }
        BAR();

        short8 af[4], bfr[4];
        #pragma unroll
        for (int fm = 0; fm < 4; fm++)
            af[fm] = *(const short8*)&As[cur][(wm + (fm << 4) + ln) * 32 + rchunk];
        #pragma unroll
        for (int fn = 0; fn < 4; fn++)
            bfr[fn] = *(const short8*)&Bs[cur][(wn + (fn << 4) + ln) * 32 + rchunk];
        #pragma unroll
        for (int fm = 0; fm < 4; fm++)
            #pragma unroll
            for (int fn = 0; fn < 4; fn++)
                acc[fm][fn] = __builtin_amdgcn_mfma_f32_16x16x32_bf16(af[fm], bfr[fn], acc[fm][fn], 0, 0, 0);

        BAR();
    }

    #pragma unroll
    for (int fm = 0; fm < 4; fm++)
        #pragma unroll
        for (int fn = 0; fn < 4; fn++) {
            int mb = m0 + wm + (fm << 4) + (g << 2);
            int n = n0 + wn + (fn << 4) + ln;
            #pragma unroll
            for (int r = 0; r < 4; r++)
                outf[(size_t)(mb + r) * N + n] = acc[fm][fn][r];
        }
    #undef GSTAGE
}

// ---------------------------------------------------------------- flash attention (swapped QK^T,
// in-register P via permlane32_swap, counted-vmcnt loop). grid = 512, 4 waves x 32 q, KV-block 64.
__global__ __launch_bounds__(256, 2) void k_attn(const u16* __restrict__ Qg, const u16* __restrict__ Kg,
                                                 const u16* __restrict__ Vtg, const float* __restrict__ bias2,
                                                 u16* __restrict__ attn_out) {
    __shared__ __align__(16) u16 Ks[2][64 * 64];
    __shared__ __align__(16) u16 Vts[2][64 * 64];
    __shared__ __align__(16) float blds4[4][1160];   // stride 1160: bank term uniform 2-way

    int t = threadIdx.x, lane = t & 63, w = t >> 6;
    int bid = blockIdx.x;
    int sid = (bid & 7) * 64 + (bid >> 3);          // XCD-aware swizzle
    int qb = sid & 7, h = (sid >> 3) & 15, b = sid >> 7;
    int q0 = qb << 7;
    const u16* Qh = Qg + ((size_t)(((b << 4) + h) * 1024 + q0)) * 64;
    const u16* Kh = Kg + (size_t)(((b << 4) + h)) * 1024 * 64;
    const u16* Vth = Vtg + (size_t)(((b << 4) + h)) * 64 * 1024;
    const float* bh = bias2 + (h << 11);

    int g = lane >> 4, ln = lane & 15;
    int lnk = (ln & 3) | ((ln & 4) << 1) | ((ln & 8) >> 1);   // kappa(ln): A-row -> K-seq remap
    int kbq = ((g & 1) << 3) | ((g >> 1) << 2);               // kappa base for D-rows 4g+r

    // Q fragments direct from global
    short8 qf[2][2];
    #pragma unroll
    for (int fm = 0; fm < 2; fm++)
        #pragma unroll
        for (int kh = 0; kh < 2; kh++)
            qf[fm][kh] = *(const short8*)(Qh + (size_t)(w * 32 + fm * 16 + ln) * 64 + kh * 32 + g * 8);

    // bias window, replicated x4 with element shifts for aligned float4 loads
    int w0 = 896 - q0;
    for (int i = t; i < 1152; i += 256) {
        float v = bh[w0 + i];
        #pragma unroll
        for (int a2 = 0; a2 < 4; a2++) { int x = i - a2; if (x >= 0) blds4[a2][x] = v; }
    }
    float b_hi = bh[1023 + 256];   // saturated bucket, rel >= 91
    float b_lo = bh[1023 - 256];   // saturated bucket, rel <= -91
    int aRep = (3 - ln) & 3;
    const float* repB = &blds4[aRep][0];

    #define STAGE(kb_, buf_)                                                                     \
        {                                                                                        \
            _Pragma("unroll")                                                                    \
            for (int r2 = 0; r2 < 2; r2++) {                                                     \
                int L = t * 16 + r2 * 4096;                                                      \
                int row = L >> 7, gI = (L >> 4) & 7, gp = gI ^ (row & 7);                        \
                __builtin_amdgcn_global_load_lds(                                                \
                    (const AS1 void*)(Kh + (size_t)((kb_) * 64 + row) * 64 + gp * 8),            \
                    (AS3 void*)&Ks[buf_][L >> 1], 16, 0, 0);                                     \
                __builtin_amdgcn_global_load_lds(                                                \
                    (const AS1 void*)(Vth + (size_t)row * 1024 + (kb_) * 64 + gp * 8),           \
                    (AS3 void*)&Vts[buf_][L >> 1], 16, 0, 0);                                    \
            }                                                                                    \
        }

    STAGE(0, 0);
    asm volatile("s_waitcnt lgkmcnt(0)" ::: "memory");   // own blds4 ds_writes drained
    __syncthreads();                                      // bias table + stage(0) published

    float psum[2] = {0.f, 0.f};
    f32x4 o[2][4];
    #pragma unroll
    for (int fm = 0; fm < 2; fm++)
        #pragma unroll
        for (int dn = 0; dn < 4; dn++) o[fm][dn] = (f32x4){0.f, 0.f, 0.f, 0.f};

    #pragma unroll 2
    for (int kb = 0; kb < 16; kb++) {
        const int cur = kb & 1;
        if (kb < 15) {
            STAGE(kb + 1, cur ^ 1);
            WAITV(4);          // stage(kb) landed; stage(kb+1) stays in flight
        } else {
            WAITV(0);
        }
        BAR();

        // ---- QK^T swapped + kappa row remap: s[fm][fn][r] = score(k = 64kb+16fn+kbq+r, q = 16fm+ln)
        f32x4 s[2][4];
        __builtin_amdgcn_s_setprio(1);
        #pragma unroll
        for (int fn = 0; fn < 4; fn++) {
            int row = (fn << 4) + lnk;
            short8 kf0 = *(const short8*)((const char*)Ks[cur] + row * 128 + (((g << 4) + 0)  ^ ((row & 7) << 4)));
            short8 kf1 = *(const short8*)((const char*)Ks[cur] + row * 128 + (((g << 4) + 64) ^ ((row & 7) << 4)));
            #pragma unroll
            for (int fm = 0; fm < 2; fm++) {
                f32x4 a = (f32x4){0.f, 0.f, 0.f, 0.f};
                a = __builtin_amdgcn_mfma_f32_16x16x32_bf16(kf0, qf[fm][0], a, 0, 0, 0);
                a = __builtin_amdgcn_mfma_f32_16x16x32_bf16(kf1, qf[fm][1], a, 0, 0, 0);
                s[fm][fn] = a;
            }
        }
        __builtin_amdgcn_s_setprio(0);

        // ---- softmax: p = exp2(s*log2e + bias); pack per quadrant into registers
        int d0 = 64 * kb - q0 - 32 * w;                     // k0 - q_wave_base
        int ibase = 64 * kb - 32 * w + 127 + kbq - ln;      // bias local index, r=0
        bool fast = (d0 >= 122) || (d0 <= -154);            // whole tile saturated
        float bu = d0 > 0 ? b_hi : b_lo;
        unsigned Px[2][4], Py[2][4];
        #pragma unroll
        for (int fm = 0; fm < 2; fm++)
            #pragma unroll
            for (int fn = 0; fn < 4; fn++) {
                f32x4 sv = s[fm][fn];
                float b0, b1, b2v, b3;
                if (fast) { b0 = b1 = b2v = b3 = bu; }
                else {
                    float4 bb = *(const float4*)(repB + (ibase + 16 * fn - 16 * fm - aRep));
                    b0 = bb.x; b1 = bb.y; b2v = bb.z; b3 = bb.w;
                }
                float p0 = EXP2(fmaf(sv[0], LOG2E, b0));
                float p1 = EXP2(fmaf(sv[1], LOG2E, b1));
                float p2 = EXP2(fmaf(sv[2], LOG2E, b2v));
                float p3 = EXP2(fmaf(sv[3], LOG2E, b3));
                psum[fm] += (p0 + p1) + (p2 + p3);
                Px[fm][fn] = pk2(p0, p1);
                Py[fm][fn] = pk2(p2, p3);
            }

        // ---- redistribute P in-register: per (fm,ks) two permlane32_swap give all 4 A-words
        short8 pa[2][2];
        #pragma unroll
        for (int fm = 0; fm < 2; fm++)
            #pragma unroll
            for (int ks = 0; ks < 2; ks++) {
                unsigned w0r = Px[fm][2 * ks], w2r = Px[fm][2 * ks + 1];
                unsigned w1r = Py[fm][2 * ks], w3r = Py[fm][2 * ks + 1];
                asm volatile("s_nop 1\n\tv_permlane32_swap_b32 %0, %1" : "+v"(w0r), "+v"(w2r));
                asm volatile("s_nop 1\n\tv_permlane32_swap_b32 %0, %1" : "+v"(w1r), "+v"(w3r));
                u32x4 tv; tv[0] = w0r; tv[1] = w1r; tv[2] = w2r; tv[3] = w3r;
                pa[fm][ks] = __builtin_bit_cast(short8, tv);
            }

        // ---- PV
        __builtin_amdgcn_s_setprio(1);
        #pragma unroll
        for (int dn = 0; dn < 4; dn++) {
            int vrow = (dn << 4) + ln;
            short8 vb0 = *(const short8*)((const char*)Vts[cur] + vrow * 128 + (((g << 4) + 0)  ^ ((vrow & 7) << 4)));
            short8 vb1 = *(const short8*)((const char*)Vts[cur] + vrow * 128 + (((g << 4) + 64) ^ ((vrow & 7) << 4)));
            #pragma unroll
            for (int fm = 0; fm < 2; fm++) {
                f32x4 a = o[fm][dn];
                a = __builtin_amdgcn_mfma_f32_16x16x32_bf16(pa[fm][0], vb0, a, 0, 0, 0);
                a = __builtin_amdgcn_mfma_f32_16x16x32_bf16(pa[fm][1], vb1, a, 0, 0, 0);
                o[fm][dn] = a;
            }
        }
        __builtin_amdgcn_s_setprio(0);

        BAR();                 // reads of buf cur done before next iter's stage overwrites it
    }

    // ---- finalize
    float linv[2][4];
    #pragma unroll
    for (int fm = 0; fm < 2; fm++) {
        float v = psum[fm];
        v += __shfl_xor(v, 16);
        v += __shfl_xor(v, 32);
        float inv = 1.0f / v;
        #pragma unroll
        for (int r = 0; r < 4; r++)
            linv[fm][r] = __shfl(inv, 4 * g + r);
    }
    #pragma unroll
    for (int fm = 0; fm < 2; fm++)
        #pragma unroll
        for (int dn = 0; dn < 4; dn++)
            #pragma unroll
            for (int r = 0; r < 4; r++) {
                int srow = q0 + 32 * w + 16 * fm + (g << 2) + r;
                int col = (h << 6) + (dn << 4) + ln;
                attn_out[((size_t)((b << 10) + srow) << 10) + col] = f2bf(o[fm][dn][r] * linv[fm][r]);
            }
}

// ---------------------------------------------------------------- launch
extern "C" void kernel_launch(void* const* d_in, const int* in_sizes, int n_in,
                              void* d_out, int out_size, void* d_ws, size_t ws_size,
                              hipStream_t stream) {
    const float* hidden = (const float*)d_in[0];
    const float* Wq = (const float*)d_in[1];
    const float* Wk = (const float*)d_in[2];
    const float* Wv = (const float*)d_in[3];
    const float* Wo = (const float*)d_in[4];
    const float* tbl = (const float*)d_in[5];

    u16* hidb = (u16*)d_ws;                       // 4096x1024 bf16
    u16* wt   = hidb + 4096 * 1024;               // 3072x1024 bf16
    u16* wot  = wt + 3072 * 1024;                 // 1024x1024 bf16
    u16* Qb   = wot + 1024 * 1024;                // [4][16][1024][64]
    u16* Kb   = Qb + 4 * 16 * 1024 * 64;          // [4][16][1024][64]
    u16* Vb   = Kb + 4 * 16 * 1024 * 64;          // [4][16][64][1024]  (transposed)
    u16* attn = Vb + 4 * 16 * 1024 * 64;          // 4096x1024 bf16
    float* bias = (float*)(attn + 4096 * 1024);   // [16][2048] f32 (folded)

    k_prep<<<dim3(32, 32, 9), 256, 0, stream>>>(hidden, Wq, Wk, Wv, Wo, tbl, hidb, wt, wot, bias);
    k_qkv<<<256, 512, 0, stream>>>(hidb, wt, Qb, Kb, Vb);
    k_attn<<<512, 256, 0, stream>>>(Qb, Kb, Vb, bias, attn);
    k_gemm_out<<<dim3(8, 32), 256, 0, stream>>>(attn, wot, (float*)d_out);
}